// Round 9
// baseline (187.421 us; speedup 1.0000x reference)
//
#include <hip/hip_runtime.h>
#include <hip/hip_bf16.h>

// PSAttentionBlock: B=16, C=KF=VF=128, H=W=128.
// out[b,f,h,w] = (v_w·x + v_b)[b,f,h,w] * S[b,h,w]
//   S[b,h,g] = sum_f softmax_{g<=h}( exp(Q[b,f]K[b,f]^T/sqrt(128)) )
//   Q/K from 1x1 conv with Weff[o,c] = qk_w[o,c]+qk_w[o,c+128]
// QK planes LINEAR in HBM. K2: balanced triangular, wave w owns row-tiles
// {w, 7-w} (9 col-tiles each), K LDS double-buffered via src-permuted staging.

using short8 = __attribute__((ext_vector_type(8))) short;
using f32x4  = __attribute__((ext_vector_type(4))) float;
typedef unsigned short u16;
typedef unsigned int   u32;

#define NB 16
#define NC 128
#define NP 16384
#define TILES_QK 4
#define TILES_V 8
#define FG 4
#define SCALE 0.08838834764831845f   // 128^-0.5

__device__ inline u16 f2bf(float f) {
  u32 u = __float_as_uint(f);
  return (u16)((u + 0x7FFFu + ((u >> 16) & 1u)) >> 16);   // RNE
}
__device__ inline u32 pk2(float a, float b) {             // 2xf32 -> packed bf16x2
  union { __hip_bfloat162 h; u32 u; } cv;
  cv.h = __float22bfloat162_rn(make_float2(a, b));
  return cv.u;
}
__device__ inline f32x4 fz4(){ f32x4 z; z[0]=0.f; z[1]=0.f; z[2]=0.f; z[3]=0.f; return z; }
// row-swizzle: XOR 16B-chunk index within a 256B row
__device__ inline int kap(int r){ return ((r ^ (r >> 2)) & 15) << 4; }

// ---------------- K0: weight prep -> bf16 ----------------
__global__ __launch_bounds__(256) void prep_w(
    const float* __restrict__ qk_w, const float* __restrict__ v_w,
    u16* __restrict__ Weff, u16* __restrict__ Vw) {
  const int i = blockIdx.x * 256 + threadIdx.x;           // 16384 threads
  #pragma unroll
  for (int r = 0; r < 2; ++r) {
    const int e = i * 2 + r;
    const int f = e >> 7, c = e & 127;
    Weff[e] = f2bf(qk_w[f * 256 + c] + qk_w[f * 256 + 128 + c]);
  }
  Vw[i] = f2bf(v_w[i]);
}

// staging helpers: [64 p][128 c] x-tile -> LDS transposed+swizzled bf16
__device__ inline void stage_issue(const float* __restrict__ xb, int tid,
                                   float4& r0, float4& r1, float4& r2, float4& r3) {
  const int c0 = (tid >> 4) * 4, p0 = (tid & 15) * 4;
  r0 = *(const float4*)(xb + (size_t)(c0 + 0) * NP + p0);
  r1 = *(const float4*)(xb + (size_t)(c0 + 1) * NP + p0);
  r2 = *(const float4*)(xb + (size_t)(c0 + 2) * NP + p0);
  r3 = *(const float4*)(xb + (size_t)(c0 + 3) * NP + p0);
}
__device__ inline void stage_write(u16* xs, int tid,
                                   float4 r0, float4 r1, float4 r2, float4 r3) {
  const int c0 = (tid >> 4) * 4, p0 = (tid & 15) * 4;
  const float* a0 = (const float*)&r0;
  const float* a1 = (const float*)&r1;
  const float* a2 = (const float*)&r2;
  const float* a3 = (const float*)&r3;
  #pragma unroll
  for (int j = 0; j < 4; ++j) {
    const int p = p0 + j;
    uint2 pk;
    pk.x = pk2(a0[j], a1[j]);
    pk.y = pk2(a2[j], a3[j]);
    *(uint2*)((char*)xs + p * 256 + ((c0 * 2) ^ kap(p))) = pk;
  }
}

// ---------------- K1: QK conv (R5-proven), coalesced restage stores ----------
// grid (64 tilegroups of 4x64p, 16 b), 512 thr; wave wv owns f [wv*32, wv*32+32)
__global__ __launch_bounds__(512, 2) void qk_conv(
    const float* __restrict__ x, const u16* __restrict__ Weff,
    const float* __restrict__ qk_b, u16* __restrict__ QK) {
  __shared__ u16 xs[2][64 * 128];             // 2 x 16 KB
  __shared__ u16 rb[8][2048];                 // 8 waves x 4 KB restage buffers
  const int b = blockIdx.y, tg = blockIdx.x, tid = threadIdx.x;
  const int wv = tid >> 6, l = tid & 63, l15 = l & 15, lq = l >> 4;
  const float* xb = x + (size_t)b * NC * NP + tg * (64 * TILES_QK);

  short8 wf[4][2];                             // tile-invariant, L2-resident
  #pragma unroll
  for (int ks = 0; ks < 4; ++ks) {
    const int cc = ks * 32 + lq * 8;
    wf[ks][0] = *(const short8*)(Weff + (size_t)(wv * 32 + l15) * 128 + cc);
    wf[ks][1] = *(const short8*)(Weff + (size_t)(wv * 32 + 16 + l15) * 128 + cc);
  }
  const float bias0 = qk_b[wv * 32 + l15];
  const float bias1 = qk_b[wv * 32 + 16 + l15];

  float4 r0, r1, r2, r3;
  stage_issue(xb, tid, r0, r1, r2, r3);
  stage_write(xs[0], tid, r0, r1, r2, r3);

  for (int t = 0; t < TILES_QK; ++t) {
    if (t + 1 < TILES_QK) stage_issue(xb + (t + 1) * 64, tid, r0, r1, r2, r3);
    __syncthreads();

    const u16* cur = xs[t & 1];
    f32x4 acc[4][2];
    #pragma unroll
    for (int m = 0; m < 4; ++m) { acc[m][0] = fz4(); acc[m][1] = fz4(); }
    #pragma unroll
    for (int ks = 0; ks < 4; ++ks) {
      const int cc2 = (ks * 32 + lq * 8) * 2;
      #pragma unroll
      for (int m = 0; m < 4; ++m) {
        const int p = m * 16 + l15;
        short8 af = *(const short8*)((const char*)cur + p * 256 + (cc2 ^ kap(p)));
        acc[m][0] = __builtin_amdgcn_mfma_f32_16x16x32_bf16(af, wf[ks][0], acc[m][0], 0, 0, 0);
        acc[m][1] = __builtin_amdgcn_mfma_f32_16x16x32_bf16(af, wf[ks][1], acc[m][1], 0, 0, 0);
      }
    }

    if (t + 1 < TILES_QK) stage_write(xs[(t + 1) & 1], tid, r0, r1, r2, r3);

    // restage acc into per-wave LDS, emit 4 fully-coalesced 16B stores
    #pragma unroll
    for (int n = 0; n < 2; ++n) {
      const int fl = n * 16 + l15;
      const float bias = n ? bias1 : bias0;
      char* rbase = (char*)rb[wv] + fl * 128;
      const int msk = (fl & 7) << 4;
      #pragma unroll
      for (int m = 0; m < 4; ++m) {
        uint2 pk;
        pk.x = pk2(acc[m][n][0] + bias, acc[m][n][1] + bias);
        pk.y = pk2(acc[m][n][2] + bias, acc[m][n][3] + bias);
        *(uint2*)(rbase + ((m * 32 + lq * 8) ^ msk)) = pk;
      }
    }
    const int pbase = tg * (64 * TILES_QK) + t * 64;
    #pragma unroll
    for (int i = 0; i < 4; ++i) {
      const int fl = i * 8 + (l >> 3), c = l & 7;
      uint4 v = *(const uint4*)((char*)rb[wv] + fl * 128 + ((c * 16) ^ ((fl & 7) << 4)));
      *(uint4*)((char*)(QK + ((size_t)(b * 256 + wv * 32 + fl) << 14)) + pbase * 2 + c * 16) = v;
    }
  }
}

// ---------------- K2: balanced-triangular scores + softmax + sum -> S ---------
// grid (32 fgroups of 4, 16 b), 256 thr = 4 waves.
// Wave w owns row-tiles rA=w and rB=7-w -> exactly 9 col-tiles (balanced).
// Tile index j: j<=w -> (rA, col j); j>w -> (rB, col j-w-1); j==w / j==8 diag.
__global__ __launch_bounds__(256, 2) void scores_softmax(
    const u16* __restrict__ QK, float* __restrict__ S) {
  __shared__ u16 Ksm[2][128 * 128];           // 2 x 32 KB
  const int b = blockIdx.y, fg = blockIdx.x, tid = threadIdx.x;
  const int wv = tid >> 6, l = tid & 63, l15 = l & 15, lq = l >> 4;
  const int rA = wv, rB = 7 - wv;

  // staging: 8 x 16B chunks/thread; src chunk permuted within its 256B row so
  // LDS content lands pre-swizzled (same cache lines -> free)
  int srcoff[8];
  #pragma unroll
  for (int s = 0; s < 8; ++s) {
    const int a = s * 256 + tid, g = a >> 4;
    srcoff[s] = ((a & ~15) | ((a & 15) ^ ((g ^ (g >> 2)) & 15))) * 16;
  }

  {
    const char* kp = (const char*)(QK + ((size_t)(b * 256 + 128 + fg * FG) << 14));
    #pragma unroll
    for (int s = 0; s < 8; ++s)
      *(uint4*)((char*)Ksm[0] + (s * 256 + tid) * 16) = *(const uint4*)(kp + srcoff[s]);
  }
  __syncthreads();

  float Sacc[9][4];
  #pragma unroll
  for (int j = 0; j < 9; ++j)
    #pragma unroll
    for (int r = 0; r < 4; ++r) Sacc[j][r] = 0.f;

  for (int fi = 0; fi < FG; ++fi) {
    const u16* kb = Ksm[fi & 1];
    const bool pf = (fi + 1 < FG);
    uint4 st[8];
    if (pf) {
      const char* kp = (const char*)(QK + ((size_t)(b * 256 + 128 + fg * FG + fi + 1) << 14));
      #pragma unroll
      for (int s = 0; s < 8; ++s) st[s] = *(const uint4*)(kp + srcoff[s]);
    }

    const char* Qp = (const char*)(QK + ((size_t)(b * 256 + fg * FG + fi) << 14));
    short8 qa[4], qb[4];
    #pragma unroll
    for (int ks = 0; ks < 4; ++ks) {
      qa[ks] = *(const short8*)(Qp + (rA * 16 + l15) * 256 + ks * 64 + lq * 16);
      qb[ks] = *(const short8*)(Qp + (rB * 16 + l15) * 256 + ks * 64 + lq * 16);
    }

    f32x4 acc[9];
    #pragma unroll
    for (int j = 0; j < 9; ++j) acc[j] = fz4();
    #pragma unroll
    for (int j = 0; j < 9; ++j) {
      if (j <= wv) {                            // row-tile rA, col-tile j
        const int g = j * 16 + l15;
        #pragma unroll
        for (int ks = 0; ks < 4; ++ks) {
          short8 bb = *(const short8*)((const char*)kb + g * 256 + ((ks * 64 + lq * 16) ^ kap(g)));
          acc[j] = __builtin_amdgcn_mfma_f32_16x16x32_bf16(qa[ks], bb, acc[j], 0, 0, 0);
        }
      } else {                                  // row-tile rB, col-tile j-wv-1
        const int g = (j - wv - 1) * 16 + l15;
        #pragma unroll
        for (int ks = 0; ks < 4; ++ks) {
          short8 bb = *(const short8*)((const char*)kb + g * 256 + ((ks * 64 + lq * 16) ^ kap(g)));
          acc[j] = __builtin_amdgcn_mfma_f32_16x16x32_bf16(qb[ks], bb, acc[j], 0, 0, 0);
        }
      }
    }

    float partA[4] = {0.f, 0.f, 0.f, 0.f};
    float partB[4] = {0.f, 0.f, 0.f, 0.f};
    #pragma unroll
    for (int j = 0; j < 9; ++j) {
      const bool isA = (j <= wv);
      const int rt = isA ? rA : rB;
      const int ct = isA ? j : (j - wv - 1);
      #pragma unroll
      for (int r = 0; r < 4; ++r) {
        float e;
        if (ct < rt) {                          // fully unmasked tile (uniform)
          e = __expf(acc[j][r] * SCALE);
        } else {                                // diagonal tile: causal mask
          const int h = rt * 16 + lq * 4 + r;
          const int g = ct * 16 + l15;
          e = (g <= h) ? __expf(acc[j][r] * SCALE) : 0.f;  // faithful: no max-sub
        }
        acc[j][r] = e;
        if (isA) partA[r] += e; else partB[r] += e;
      }
    }
    #pragma unroll
    for (int r = 0; r < 4; ++r) {               // reduce across 16-lane groups
      partA[r] += __shfl_xor(partA[r], 1);
      partA[r] += __shfl_xor(partA[r], 2);
      partA[r] += __shfl_xor(partA[r], 4);
      partA[r] += __shfl_xor(partA[r], 8);
      partB[r] += __shfl_xor(partB[r], 1);
      partB[r] += __shfl_xor(partB[r], 2);
      partB[r] += __shfl_xor(partB[r], 4);
      partB[r] += __shfl_xor(partB[r], 8);
    }
    #pragma unroll
    for (int r = 0; r < 4; ++r) { partA[r] = 1.0f / partA[r]; partB[r] = 1.0f / partB[r]; }
    #pragma unroll
    for (int j = 0; j < 9; ++j)
      #pragma unroll
      for (int r = 0; r < 4; ++r)
        Sacc[j][r] += acc[j][r] * ((j <= wv) ? partA[r] : partB[r]);

    if (pf) {
      char* kd = (char*)Ksm[(fi & 1) ^ 1];
      #pragma unroll
      for (int s = 0; s < 8; ++s)
        *(uint4*)(kd + (s * 256 + tid) * 16) = st[s];
    }
    __syncthreads();
  }

  #pragma unroll
  for (int j = 0; j < 9; ++j) {
    const bool isA = (j <= wv);
    const int rt = isA ? rA : rB;
    const int ct = isA ? j : (j - wv - 1);
    #pragma unroll
    for (int r = 0; r < 4; ++r) {
      const int h = rt * 16 + lq * 4 + r, g = ct * 16 + l15;
      atomicAdd(&S[(size_t)b * NP + h * 128 + g], Sacc[j][r]);
    }
  }
}

// ---------------- K3: V conv + scale by S -> out, depth-2 prefetch ----------------
__device__ inline void v_compute(const u16* cur, int l15, int lq,
                                 f32x4 acc[4], const short8 wf[4]) {
  #pragma unroll
  for (int m = 0; m < 4; ++m) acc[m] = fz4();
  #pragma unroll
  for (int ks = 0; ks < 4; ++ks) {
    const int cc2 = (ks * 32 + lq * 8) * 2;
    #pragma unroll
    for (int m = 0; m < 4; ++m) {
      const int p = m * 16 + l15;
      short8 af = *(const short8*)((const char*)cur + p * 256 + (cc2 ^ kap(p)));
      acc[m] = __builtin_amdgcn_mfma_f32_16x16x32_bf16(af, wf[ks], acc[m], 0, 0, 0);
    }
  }
}
__device__ inline void v_store(float* orow, const float* Sb, int lq,
                               const f32x4 acc[4], int pbase, float vb) {
  #pragma unroll
  for (int m = 0; m < 4; ++m) {
    const int p = pbase + m * 16 + lq * 4;
    float4 sv = *(const float4*)(Sb + p);
    float4 o;
    o.x = (acc[m][0] + vb) * sv.x;
    o.y = (acc[m][1] + vb) * sv.y;
    o.z = (acc[m][2] + vb) * sv.z;
    o.w = (acc[m][3] + vb) * sv.w;
    *(float4*)(orow + p) = o;
  }
}

// grid (32 tilegroups, 16 b), 512 thr; wave wv owns f [wv*16, wv*16+16)
__global__ __launch_bounds__(512, 2) void v_conv_mul(
    const float* __restrict__ x, const u16* __restrict__ Vw,
    const float* __restrict__ v_b, const float* __restrict__ S,
    float* __restrict__ out) {
  __shared__ u16 xs[2][64 * 128];
  const int b = blockIdx.y, tg = blockIdx.x, tid = threadIdx.x;
  const int wv = tid >> 6, l = tid & 63, l15 = l & 15, lq = l >> 4;
  const float* xb = x + (size_t)b * NC * NP + tg * (64 * TILES_V);

  short8 wf[4];
  #pragma unroll
  for (int ks = 0; ks < 4; ++ks)
    wf[ks] = *(const short8*)(Vw + (size_t)(wv * 16 + l15) * 128 + ks * 32 + lq * 8);
  const int f = wv * 16 + l15;
  const float vb = v_b[f];
  float* orow = out + (size_t)(b * 128 + f) * NP;
  const float* Sb = S + (size_t)b * NP;

  float4 A0, A1, A2, A3, B0, B1, B2, B3;
  stage_issue(xb, tid, A0, A1, A2, A3);
  stage_write(xs[0], tid, A0, A1, A2, A3);
  stage_issue(xb + 64, tid, B0, B1, B2, B3);

  f32x4 acc[4];
  #pragma unroll
  for (int tp = 0; tp < TILES_V; tp += 2) {
    __syncthreads();
    if (tp + 2 < TILES_V) stage_issue(xb + (tp + 2) * 64, tid, A0, A1, A2, A3);
    v_compute(xs[0], l15, lq, acc, wf);
    if (tp + 1 < TILES_V) stage_write(xs[1], tid, B0, B1, B2, B3);
    v_store(orow, Sb, lq, acc, tg * (64 * TILES_V) + tp * 64, vb);
    __syncthreads();
    if (tp + 3 < TILES_V) stage_issue(xb + (tp + 3) * 64, tid, B0, B1, B2, B3);
    v_compute(xs[1], l15, lq, acc, wf);
    if (tp + 2 < TILES_V) stage_write(xs[0], tid, A0, A1, A2, A3);
    v_store(orow, Sb, lq, acc, tg * (64 * TILES_V) + (tp + 1) * 64, vb);
  }
}

extern "C" void kernel_launch(void* const* d_in, const int* in_sizes, int n_in,
                              void* d_out, int out_size, void* d_ws, size_t ws_size,
                              hipStream_t stream) {
  const float* x    = (const float*)d_in[0];
  const float* qk_w = (const float*)d_in[1];
  const float* qk_b = (const float*)d_in[2];
  const float* v_w  = (const float*)d_in[3];
  const float* v_b  = (const float*)d_in[4];
  float* out = (float*)d_out;

  char* ws = (char*)d_ws;
  u16*   QK   = (u16*)ws;                                  // 134,217,728 B
  float* S    = (float*)(ws + (size_t)134217728);          //   1,048,576 B
  u16*   Weff = (u16*)(ws + (size_t)134217728 + 1048576);  //      65,536 B
  u16*   Vw   = (u16*)(ws + (size_t)134217728 + 1048576 + 65536);  // 32,768 B

  prep_w<<<64, 256, 0, stream>>>(qk_w, v_w, Weff, Vw);
  qk_conv<<<dim3(64, 16), 512, 0, stream>>>(x, Weff, qk_b, QK);
  (void)hipMemsetAsync(S, 0, (size_t)NB * NP * sizeof(float), stream);
  scores_softmax<<<dim3(32, 16), 256, 0, stream>>>(QK, S);
  v_conv_mul<<<dim3(32, 16), 512, 0, stream>>>(x, Vw, v_b, S, out);
}

// Round 10
// 153.908 us; speedup vs baseline: 1.2177x; 1.2177x over previous
//
#include <hip/hip_runtime.h>
#include <hip/hip_bf16.h>

// PSAttentionBlock: B=16, C=KF=VF=128, H=W=128.
// out[b,f,h,w] = (v_w·x + v_b)[b,f,h,w] * S[b,h,w]
//   S[b,h,g] = sum_f softmax_{g<=h}( exp(Q[b,f]K[b,f]^T/sqrt(128)) )
//   Q/K from 1x1 conv with Weff[o,c] = qk_w[o,c]+qk_w[o,c+128]
// QK planes LINEAR in HBM (coalesced stores); K2 swizzles its LDS copy by
// permuting the global SOURCE address. K1/K3 use raw s_barrier with
// lgkmcnt-only drain: VMEM loads/stores stay in flight across barriers (T3).

using short8 = __attribute__((ext_vector_type(8))) short;
using f32x4  = __attribute__((ext_vector_type(4))) float;
typedef unsigned short u16;
typedef unsigned int   u32;

#define NB 16
#define NC 128
#define NP 16384
#define TILES_QK 4
#define TILES_V 8
#define SCALE 0.08838834764831845f   // 128^-0.5

__device__ inline u16 f2bf(float f) {
  u32 u = __float_as_uint(f);
  return (u16)((u + 0x7FFFu + ((u >> 16) & 1u)) >> 16);   // RNE
}
__device__ inline u32 pk2(float a, float b) {             // 2xf32 -> packed bf16x2
  union { __hip_bfloat162 h; u32 u; } cv;
  cv.h = __float22bfloat162_rn(make_float2(a, b));
  return cv.u;
}
__device__ inline f32x4 fz4(){ f32x4 z; z[0]=0.f; z[1]=0.f; z[2]=0.f; z[3]=0.f; return z; }
// row-swizzle: XOR 16B-chunk index within a 256B row
__device__ inline int kap(int r){ return ((r ^ (r >> 2)) & 15) << 4; }

// barrier that drains ONLY LDS (lgkm) — global loads/stores keep flying.
// __syncthreads() would emit s_waitcnt vmcnt(0) and stall on in-flight VMEM.
__device__ inline void barrier_lgkm() {
  __builtin_amdgcn_sched_barrier(0);
  asm volatile("s_waitcnt lgkmcnt(0)" ::: "memory");
  __builtin_amdgcn_s_barrier();
  __builtin_amdgcn_sched_barrier(0);
}

// ---------------- K0: weight prep -> bf16 ----------------
__global__ __launch_bounds__(256) void prep_w(
    const float* __restrict__ qk_w, const float* __restrict__ v_w,
    u16* __restrict__ Weff, u16* __restrict__ Vw) {
  const int i = blockIdx.x * 256 + threadIdx.x;           // 16384 threads
  #pragma unroll
  for (int r = 0; r < 2; ++r) {
    const int e = i * 2 + r;
    const int f = e >> 7, c = e & 127;
    Weff[e] = f2bf(qk_w[f * 256 + c] + qk_w[f * 256 + 128 + c]);
  }
  Vw[i] = f2bf(v_w[i]);
}

// staging helpers: [64 p][128 c] x-tile -> LDS transposed+swizzled bf16
__device__ inline void stage_issue(const float* __restrict__ xb, int tid,
                                   float4& r0, float4& r1, float4& r2, float4& r3) {
  const int c0 = (tid >> 4) * 4, p0 = (tid & 15) * 4;
  r0 = *(const float4*)(xb + (size_t)(c0 + 0) * NP + p0);
  r1 = *(const float4*)(xb + (size_t)(c0 + 1) * NP + p0);
  r2 = *(const float4*)(xb + (size_t)(c0 + 2) * NP + p0);
  r3 = *(const float4*)(xb + (size_t)(c0 + 3) * NP + p0);
}
__device__ inline void stage_write(u16* xs, int tid,
                                   float4 r0, float4 r1, float4 r2, float4 r3) {
  const int c0 = (tid >> 4) * 4, p0 = (tid & 15) * 4;
  const float* a0 = (const float*)&r0;
  const float* a1 = (const float*)&r1;
  const float* a2 = (const float*)&r2;
  const float* a3 = (const float*)&r3;
  #pragma unroll
  for (int j = 0; j < 4; ++j) {
    const int p = p0 + j;
    uint2 pk;
    pk.x = pk2(a0[j], a1[j]);
    pk.y = pk2(a2[j], a3[j]);
    *(uint2*)((char*)xs + p * 256 + ((c0 * 2) ^ kap(p))) = pk;
  }
}

// ---------------- K1: QK conv, coalesced restage stores, lgkm-only barrier ---
// grid (64 tilegroups of 4x64p, 16 b), 512 thr; wave wv owns f [wv*32, wv*32+32)
__global__ __launch_bounds__(512, 2) void qk_conv(
    const float* __restrict__ x, const u16* __restrict__ Weff,
    const float* __restrict__ qk_b, u16* __restrict__ QK) {
  __shared__ u16 xs[2][64 * 128];             // 2 x 16 KB
  __shared__ u16 rb[8][2048];                 // 8 waves x 4 KB restage buffers
  const int b = blockIdx.y, tg = blockIdx.x, tid = threadIdx.x;
  const int wv = tid >> 6, l = tid & 63, l15 = l & 15, lq = l >> 4;
  const float* xb = x + (size_t)b * NC * NP + tg * (64 * TILES_QK);

  short8 wf[4][2];                             // tile-invariant, L2-resident
  #pragma unroll
  for (int ks = 0; ks < 4; ++ks) {
    const int cc = ks * 32 + lq * 8;
    wf[ks][0] = *(const short8*)(Weff + (size_t)(wv * 32 + l15) * 128 + cc);
    wf[ks][1] = *(const short8*)(Weff + (size_t)(wv * 32 + 16 + l15) * 128 + cc);
  }
  const float bias0 = qk_b[wv * 32 + l15];
  const float bias1 = qk_b[wv * 32 + 16 + l15];

  float4 r0, r1, r2, r3;
  stage_issue(xb, tid, r0, r1, r2, r3);
  stage_write(xs[0], tid, r0, r1, r2, r3);

  for (int t = 0; t < TILES_QK; ++t) {
    if (t + 1 < TILES_QK) stage_issue(xb + (t + 1) * 64, tid, r0, r1, r2, r3);
    barrier_lgkm();

    const u16* cur = xs[t & 1];
    f32x4 acc[4][2];
    #pragma unroll
    for (int m = 0; m < 4; ++m) { acc[m][0] = fz4(); acc[m][1] = fz4(); }
    #pragma unroll
    for (int ks = 0; ks < 4; ++ks) {
      const int cc2 = (ks * 32 + lq * 8) * 2;
      #pragma unroll
      for (int m = 0; m < 4; ++m) {
        const int p = m * 16 + l15;
        short8 af = *(const short8*)((const char*)cur + p * 256 + (cc2 ^ kap(p)));
        acc[m][0] = __builtin_amdgcn_mfma_f32_16x16x32_bf16(af, wf[ks][0], acc[m][0], 0, 0, 0);
        acc[m][1] = __builtin_amdgcn_mfma_f32_16x16x32_bf16(af, wf[ks][1], acc[m][1], 0, 0, 0);
      }
    }

    if (t + 1 < TILES_QK) stage_write(xs[(t + 1) & 1], tid, r0, r1, r2, r3);

    // restage acc into per-wave LDS, emit 4 fully-coalesced 16B stores
    #pragma unroll
    for (int n = 0; n < 2; ++n) {
      const int fl = n * 16 + l15;
      const float bias = n ? bias1 : bias0;
      char* rbase = (char*)rb[wv] + fl * 128;
      const int msk = (fl & 7) << 4;
      #pragma unroll
      for (int m = 0; m < 4; ++m) {
        uint2 pk;
        pk.x = pk2(acc[m][n][0] + bias, acc[m][n][1] + bias);
        pk.y = pk2(acc[m][n][2] + bias, acc[m][n][3] + bias);
        *(uint2*)(rbase + ((m * 32 + lq * 8) ^ msk)) = pk;
      }
    }
    const int pbase = tg * (64 * TILES_QK) + t * 64;
    #pragma unroll
    for (int i = 0; i < 4; ++i) {
      const int fl = i * 8 + (l >> 3), c = l & 7;
      uint4 v = *(const uint4*)((char*)rb[wv] + fl * 128 + ((c * 16) ^ ((fl & 7) << 4)));
      *(uint4*)((char*)(QK + ((size_t)(b * 256 + wv * 32 + fl) << 14)) + pbase * 2 + c * 16) = v;
    }
  }
}

// ---------------- K2: scores + causal softmax + sum over f -> S (R5) ---------
// grid (16 fgroups of 8, 16 b), 512 thr; wave wv owns rows h [wv*16, wv*16+16)
__global__ __launch_bounds__(512, 2) void scores_softmax(
    const u16* __restrict__ QK, float* __restrict__ S) {
  __shared__ u16 Ksm[2][128 * 128];           // 2 x 32 KB
  const int b = blockIdx.y, fg = blockIdx.x, tid = threadIdx.x;
  const int wv = tid >> 6, l = tid & 63, l15 = l & 15, lq = l >> 4;
  const int hbase = wv * 16;

  // per-thread staging offsets: dest chunk linear, src chunk permuted within
  // its 256B row so LDS content lands pre-swizzled (same cache lines -> free)
  int srcoff[4];
  #pragma unroll
  for (int s = 0; s < 4; ++s) {
    const int a = s * 512 + tid, g = a >> 4;
    srcoff[s] = ((a & ~15) | ((a & 15) ^ ((g ^ (g >> 2)) & 15))) * 16;
  }

  {
    const char* kp = (const char*)(QK + ((size_t)(b * 256 + 128 + fg * 8) << 14));
    #pragma unroll
    for (int s = 0; s < 4; ++s)
      *(uint4*)((char*)Ksm[0] + (s * 512 + tid) * 16) = *(const uint4*)(kp + srcoff[s]);
  }
  __syncthreads();

  float Sacc[8][4];
  #pragma unroll
  for (int n = 0; n < 8; ++n)
    #pragma unroll
    for (int r = 0; r < 4; ++r) Sacc[n][r] = 0.f;

  for (int fi = 0; fi < 8; ++fi) {
    const u16* kb = Ksm[fi & 1];
    const bool pf = (fi < 7);
    uint4 st0, st1, st2, st3;
    if (pf) {
      const char* kp = (const char*)(QK + ((size_t)(b * 256 + 128 + fg * 8 + fi + 1) << 14));
      st0 = *(const uint4*)(kp + srcoff[0]);
      st1 = *(const uint4*)(kp + srcoff[1]);
      st2 = *(const uint4*)(kp + srcoff[2]);
      st3 = *(const uint4*)(kp + srcoff[3]);
    }

    const char* Qp = (const char*)(QK + ((size_t)(b * 256 + fg * 8 + fi) << 14));
    f32x4 acc[8];
    #pragma unroll
    for (int n = 0; n < 8; ++n) acc[n] = fz4();
    #pragma unroll
    for (int ks = 0; ks < 4; ++ks) {
      const int cc2 = (ks * 32 + lq * 8) * 2;
      const int hq = hbase + l15;
      short8 a = *(const short8*)(Qp + hq * 256 + cc2);        // linear Q read
      #pragma unroll
      for (int n = 0; n < 8; ++n) {
        const int g = n * 16 + l15;
        short8 bb = *(const short8*)((const char*)kb + g * 256 + (cc2 ^ kap(g)));
        acc[n] = __builtin_amdgcn_mfma_f32_16x16x32_bf16(a, bb, acc[n], 0, 0, 0);
      }
    }

    float part[4] = {0.f, 0.f, 0.f, 0.f};
    #pragma unroll
    for (int n = 0; n < 8; ++n)
      #pragma unroll
      for (int r = 0; r < 4; ++r) {
        const int h = hbase + lq * 4 + r;
        const int g = n * 16 + l15;
        float e = (g <= h) ? __expf(acc[n][r] * SCALE) : 0.f;   // faithful: no max-sub
        acc[n][r] = e;
        part[r] += e;
      }
    #pragma unroll
    for (int r = 0; r < 4; ++r) {
      part[r] += __shfl_xor(part[r], 1);
      part[r] += __shfl_xor(part[r], 2);
      part[r] += __shfl_xor(part[r], 4);
      part[r] += __shfl_xor(part[r], 8);
    }
    #pragma unroll
    for (int r = 0; r < 4; ++r) part[r] = 1.0f / part[r];
    #pragma unroll
    for (int n = 0; n < 8; ++n)
      #pragma unroll
      for (int r = 0; r < 4; ++r) Sacc[n][r] += acc[n][r] * part[r];

    if (pf) {
      char* kd = (char*)Ksm[(fi & 1) ^ 1];
      *(uint4*)(kd + (0 * 512 + tid) * 16) = st0;
      *(uint4*)(kd + (1 * 512 + tid) * 16) = st1;
      *(uint4*)(kd + (2 * 512 + tid) * 16) = st2;
      *(uint4*)(kd + (3 * 512 + tid) * 16) = st3;
    }
    __syncthreads();
  }

  #pragma unroll
  for (int n = 0; n < 8; ++n)
    #pragma unroll
    for (int r = 0; r < 4; ++r) {
      const int h = hbase + lq * 4 + r, g = n * 16 + l15;
      atomicAdd(&S[(size_t)b * NP + h * 128 + g], Sacc[n][r]);
    }
}

// ---------------- K3: V conv + scale by S -> out, depth-2, lgkm barrier ------
__device__ inline void v_compute(const u16* cur, int l15, int lq,
                                 f32x4 acc[4], const short8 wf[4]) {
  #pragma unroll
  for (int m = 0; m < 4; ++m) acc[m] = fz4();
  #pragma unroll
  for (int ks = 0; ks < 4; ++ks) {
    const int cc2 = (ks * 32 + lq * 8) * 2;
    #pragma unroll
    for (int m = 0; m < 4; ++m) {
      const int p = m * 16 + l15;
      short8 af = *(const short8*)((const char*)cur + p * 256 + (cc2 ^ kap(p)));
      acc[m] = __builtin_amdgcn_mfma_f32_16x16x32_bf16(af, wf[ks], acc[m], 0, 0, 0);
    }
  }
}
__device__ inline void v_store(float* orow, const float* Sb, int lq,
                               const f32x4 acc[4], int pbase, float vb) {
  #pragma unroll
  for (int m = 0; m < 4; ++m) {
    const int p = pbase + m * 16 + lq * 4;
    float4 sv = *(const float4*)(Sb + p);
    float4 o;
    o.x = (acc[m][0] + vb) * sv.x;
    o.y = (acc[m][1] + vb) * sv.y;
    o.z = (acc[m][2] + vb) * sv.z;
    o.w = (acc[m][3] + vb) * sv.w;
    *(float4*)(orow + p) = o;
  }
}

// grid (32 tilegroups, 16 b), 512 thr; wave wv owns f [wv*16, wv*16+16)
__global__ __launch_bounds__(512, 2) void v_conv_mul(
    const float* __restrict__ x, const u16* __restrict__ Vw,
    const float* __restrict__ v_b, const float* __restrict__ S,
    float* __restrict__ out) {
  __shared__ u16 xs[2][64 * 128];
  const int b = blockIdx.y, tg = blockIdx.x, tid = threadIdx.x;
  const int wv = tid >> 6, l = tid & 63, l15 = l & 15, lq = l >> 4;
  const float* xb = x + (size_t)b * NC * NP + tg * (64 * TILES_V);

  short8 wf[4];
  #pragma unroll
  for (int ks = 0; ks < 4; ++ks)
    wf[ks] = *(const short8*)(Vw + (size_t)(wv * 16 + l15) * 128 + ks * 32 + lq * 8);
  const int f = wv * 16 + l15;
  const float vb = v_b[f];
  float* orow = out + (size_t)(b * 128 + f) * NP;
  const float* Sb = S + (size_t)b * NP;

  float4 A0, A1, A2, A3, B0, B1, B2, B3;
  stage_issue(xb, tid, A0, A1, A2, A3);
  stage_write(xs[0], tid, A0, A1, A2, A3);
  stage_issue(xb + 64, tid, B0, B1, B2, B3);

  f32x4 acc[4];
  #pragma unroll
  for (int tp = 0; tp < TILES_V; tp += 2) {
    barrier_lgkm();
    if (tp + 2 < TILES_V) stage_issue(xb + (tp + 2) * 64, tid, A0, A1, A2, A3);
    v_compute(xs[0], l15, lq, acc, wf);
    if (tp + 1 < TILES_V) stage_write(xs[1], tid, B0, B1, B2, B3);
    v_store(orow, Sb, lq, acc, tg * (64 * TILES_V) + tp * 64, vb);
    barrier_lgkm();
    if (tp + 3 < TILES_V) stage_issue(xb + (tp + 3) * 64, tid, B0, B1, B2, B3);
    v_compute(xs[1], l15, lq, acc, wf);
    if (tp + 2 < TILES_V) stage_write(xs[0], tid, A0, A1, A2, A3);
    v_store(orow, Sb, lq, acc, tg * (64 * TILES_V) + (tp + 1) * 64, vb);
  }
}

extern "C" void kernel_launch(void* const* d_in, const int* in_sizes, int n_in,
                              void* d_out, int out_size, void* d_ws, size_t ws_size,
                              hipStream_t stream) {
  const float* x    = (const float*)d_in[0];
  const float* qk_w = (const float*)d_in[1];
  const float* qk_b = (const float*)d_in[2];
  const float* v_w  = (const float*)d_in[3];
  const float* v_b  = (const float*)d_in[4];
  float* out = (float*)d_out;

  char* ws = (char*)d_ws;
  u16*   QK   = (u16*)ws;                                  // 134,217,728 B
  float* S    = (float*)(ws + (size_t)134217728);          //   1,048,576 B
  u16*   Weff = (u16*)(ws + (size_t)134217728 + 1048576);  //      65,536 B
  u16*   Vw   = (u16*)(ws + (size_t)134217728 + 1048576 + 65536);  // 32,768 B

  prep_w<<<64, 256, 0, stream>>>(qk_w, v_w, Weff, Vw);
  qk_conv<<<dim3(64, 16), 512, 0, stream>>>(x, Weff, qk_b, QK);
  (void)hipMemsetAsync(S, 0, (size_t)NB * NP * sizeof(float), stream);
  scores_softmax<<<dim3(16, 16), 512, 0, stream>>>(QK, S);
  v_conv_mul<<<dim3(32, 16), 512, 0, stream>>>(x, Vw, v_b, S, out);
}